// Round 1
// baseline (154.971 us; speedup 1.0000x reference)
//
#include <hip/hip_runtime.h>
#include <stdint.h>

#define NH 12
#define DH 64
#define SEQ 4096
#define DM 768
#define NEGV -1e9f

using bf16x8 = __attribute__((ext_vector_type(8))) short;
using f32x4  = __attribute__((ext_vector_type(4))) float;

static __device__ __forceinline__ short f2bf(float f) {
  unsigned u = __builtin_bit_cast(unsigned, f);
  u += 0x7fffu + ((u >> 16) & 1u);
  return (short)(u >> 16);
}

static __device__ __forceinline__ void gload16(const void* g, void* l) {
  __builtin_amdgcn_global_load_lds(
      (const __attribute__((address_space(1))) unsigned*)g,
      (__attribute__((address_space(3))) unsigned*)l, 16, 0, 0);
}

static __device__ __forceinline__ f32x4 mfma16(bf16x8 a, bf16x8 b, f32x4 c) {
  return __builtin_amdgcn_mfma_f32_16x16x32_bf16(a, b, c, 0, 0, 0);
}

// ---------------- conversion kernels ----------------
__global__ __launch_bounds__(256) void cvt_x(const float* __restrict__ X,
                                             short* __restrict__ Xb, int n4) {
  int i = blockIdx.x * 256 + threadIdx.x;
  if (i >= n4) return;
  float4 v = ((const float4*)X)[i];
  short4 o; o.x = f2bf(v.x); o.y = f2bf(v.y); o.z = f2bf(v.z); o.w = f2bf(v.w);
  ((short4*)Xb)[i] = o;
}

__global__ __launch_bounds__(256) void cvt_w(
    const float* __restrict__ Wq, const float* __restrict__ Wk,
    const float* __restrict__ Wv, const float* __restrict__ Wo,
    short* __restrict__ Wqkv, short* __restrict__ Wob) {
  int i = blockIdx.x * 256 + threadIdx.x;  // unit = 4 elems
  const int n1 = 2304 * 768 / 4;
  if (i < n1) {
    int e = i * 4;
    int row = e / 768;
    const float* src;
    float sc = 1.0f;
    if (row < 768)       { src = Wq + e; sc = 0.125f; }     // fold 1/sqrt(dh)
    else if (row < 1536) { src = Wk + e - 768 * 768; }
    else                 { src = Wv + e - 1536 * 768; }
    float4 v = *(const float4*)src;
    short4 o; o.x = f2bf(v.x * sc); o.y = f2bf(v.y * sc);
    o.z = f2bf(v.z * sc); o.w = f2bf(v.w * sc);
    ((short4*)Wqkv)[i] = o;
  } else {
    int j = i - n1;
    if (j >= 768 * 768 / 4) return;
    float4 v = ((const float4*)Wo)[j];
    short4 o; o.x = f2bf(v.x); o.y = f2bf(v.y); o.z = f2bf(v.z); o.w = f2bf(v.w);
    ((short4*)Wob)[j] = o;
  }
}

// ---------------- QKV projection GEMM (m97 structure) ----------------
// C[m,n] = sum_k Xb[m,k] * Wqkv[n,k]; epilogue scatters q/k ([B,H,S,64]) or vT ([B,H,64,S])
__global__ __launch_bounds__(256) void gemm_qkv(
    const short* __restrict__ Xb, const short* __restrict__ Wqkv,
    const float* __restrict__ bq, const float* __restrict__ bk,
    const float* __restrict__ bv,
    short* __restrict__ qO, short* __restrict__ kO, short* __restrict__ vT) {
  __shared__ __align__(16) short sm[128 * 132];  // K-loop: As=sm[0..4095], Bs=sm[4096..8191]
  short* As = sm;
  short* Bs = sm + 4096;
  const int tid = threadIdx.x, lane = tid & 63, wid = tid >> 6;
  const int m0 = blockIdx.x * 128, n0 = blockIdx.y * 128;
  const int wr = (wid >> 1) * 64, wc = (wid & 1) * 64;
  const int K = 768;
  const short* Ag = Xb + (m0 + (tid >> 2)) * K + ((tid & 3) << 3);
  const short* Bg = Wqkv + (n0 + (tid >> 2)) * K + ((tid & 3) << 3);
  short* Al = As + tid * 8;
  short* Bl = Bs + tid * 8;
  f32x4 acc[4][4] = {};
  for (int kt = 0; kt < K; kt += 32) {
    __syncthreads();
    gload16(Ag + kt, Al);
    gload16(Ag + kt + 64 * K, Al + 2048);
    gload16(Bg + kt, Bl);
    gload16(Bg + kt + 64 * K, Bl + 2048);
    __syncthreads();
    bf16x8 a[4], b[4];
#pragma unroll
    for (int mi = 0; mi < 4; ++mi)
      a[mi] = *(const bf16x8*)&As[(wr + mi * 16 + (lane & 15)) * 32 + ((lane >> 4) << 3)];
#pragma unroll
    for (int ni = 0; ni < 4; ++ni)
      b[ni] = *(const bf16x8*)&Bs[(wc + ni * 16 + (lane & 15)) * 32 + ((lane >> 4) << 3)];
#pragma unroll
    for (int mi = 0; mi < 4; ++mi)
#pragma unroll
      for (int ni = 0; ni < 4; ++ni)
        acc[mi][ni] = mfma16(a[mi], b[ni], acc[mi][ni]);
  }
  const int src = n0 / 768;  // 0=q 1=k 2=v
  const int bb = m0 >> 12;
  const int s0 = m0 & (SEQ - 1);
  const int nloc = n0 % 768;
  float bias[4];
#pragma unroll
  for (int ni = 0; ni < 4; ++ni) {
    int c = wc + ni * 16 + (lane & 15);
    bias[ni] = (src == 0) ? bq[nloc + c] * 0.125f
             : (src == 1) ? bk[nloc + c] : bv[nloc + c];
  }
  __syncthreads();
  if (src < 2) {
    // [row][col] stride 132 (pad breaks bank alignment)
#pragma unroll
    for (int mi = 0; mi < 4; ++mi)
#pragma unroll
      for (int ni = 0; ni < 4; ++ni) {
        int row = wr + mi * 16 + ((lane >> 4) << 2);
        int col = wc + ni * 16 + (lane & 15);
#pragma unroll
        for (int r = 0; r < 4; ++r)
          sm[(row + r) * 132 + col] = f2bf(acc[mi][ni][r] + bias[ni]);
      }
    __syncthreads();
    short* dst = (src == 0) ? qO : kO;
    for (int u = tid; u < 8192; u += 256) {
      int r = u >> 6, cp = (u & 63) << 1;
      unsigned val = *(const unsigned*)&sm[r * 132 + cp];
      int c = nloc + cp;
      int h = c >> 6, d = c & 63;
      *(unsigned*)&dst[(((bb * NH + h) * SEQ) + s0 + r) * DH + d] = val;
    }
  } else {
    // transposed [col][row] stride 132, pack 4 rows/write
#pragma unroll
    for (int mi = 0; mi < 4; ++mi)
#pragma unroll
      for (int ni = 0; ni < 4; ++ni) {
        int row = wr + mi * 16 + ((lane >> 4) << 2);
        int col = wc + ni * 16 + (lane & 15);
        short4 pk;
        pk.x = f2bf(acc[mi][ni][0] + bias[ni]);
        pk.y = f2bf(acc[mi][ni][1] + bias[ni]);
        pk.z = f2bf(acc[mi][ni][2] + bias[ni]);
        pk.w = f2bf(acc[mi][ni][3] + bias[ni]);
        *(short4*)&sm[col * 132 + row] = pk;
      }
    __syncthreads();
    for (int u = tid; u < 8192; u += 256) {
      int cc = u >> 6, rp = (u & 63) << 1;
      unsigned val = *(const unsigned*)&sm[cc * 132 + rp];
      int c = nloc + cc;
      int h = c >> 6, d = c & 63;
      *(unsigned*)&vT[(((bb * NH + h) * DH) + d) * SEQ + s0 + rp] = val;
    }
  }
}

// ---------------- sliding-window attention ----------------
// grid (64 strips, 12 heads, 2 batch); 4 waves; wave w owns 16 q-rows.
__global__ __launch_bounds__(256) void attn(
    const short* __restrict__ qI, const short* __restrict__ kI,
    const short* __restrict__ vT, const float* __restrict__ amask,
    short* __restrict__ ctx) {
  __shared__ __align__(16) short Ks[128 * 64];   // [j][d], XOR-swizzled chunks
  __shared__ __align__(16) short Vs[64 * 128];   // [d][j], XOR-swizzled chunks
  __shared__ float BiasS[128];
  __shared__ __align__(16) short Ps[4][16 * 132];
  const int tid = threadIdx.x, lane = tid & 63, wid = tid >> 6;
  const int strip = blockIdx.x, h = blockIdx.y, bb = blockIdx.z;
  const int s0 = strip * 64;
  const int n = s0 >> 8;       // 256-block index
  const int i0 = s0 & 255;     // strip offset within block
  const int bh = bb * NH + h;

  const short* qbase = qI + ((bh * SEQ) + s0 + wid * 16) * DH;
  bf16x8 aq[2];
#pragma unroll
  for (int ks = 0; ks < 2; ++ks)
    aq[ks] = *(const bf16x8*)(qbase + (lane & 15) * DH + ks * 32 + ((lane >> 4) << 3));

  f32x4 acc[4] = {};
  float mrow[4], lrow[4];
#pragma unroll
  for (int r = 0; r < 4; ++r) { mrow[r] = -3e38f; lrow[r] = 0.f; }

  const int iw = i0 + wid * 16;
  const short* kbase0 = kI + bh * SEQ * DH;
  const short* vbase0 = vT + bh * DH * SEQ;

#pragma unroll 1
  for (int c = 0; c < 6; ++c) {
    const int j0 = c * 128;
    const int kpos0 = (n - 1) * 256 + j0;          // chunk never partially OOB
    if (kpos0 < 0 || kpos0 >= SEQ) continue;       // uniform skip
    if (j0 + 127 < i0 || j0 > i0 + 63 + 512) continue;  // band skip (uniform)

    __syncthreads();
    {
      const short* kb = kbase0 + kpos0 * DH;
#pragma unroll
      for (int it = 0; it < 4; ++it) {
        int e = it * 2048 + tid * 8;
        int j = e >> 6;
        int ch = (e >> 3) & 7;
        gload16(kb + j * DH + (((ch ^ (j & 7)) << 3)), (short*)Ks + e);
      }
      const short* vb = vbase0 + kpos0;
#pragma unroll
      for (int it = 0; it < 4; ++it) {
        int e = it * 2048 + tid * 8;
        int d = e >> 7;
        int ch = (e >> 3) & 15;
        gload16(vb + d * SEQ + (((ch ^ (d & 7)) << 3)), (short*)Vs + e);
      }
      if (tid < 128) BiasS[tid] = -amask[bb * SEQ + kpos0 + tid];
    }
    __syncthreads();

    // QK^T: 16 rows x 128 keys
    f32x4 sc[8];
#pragma unroll
    for (int jt = 0; jt < 8; ++jt) {
      int j = jt * 16 + (lane & 15);
      int c0 = (lane >> 4) << 3;
      int e0 = j * DH + (((c0 >> 3) ^ (j & 7)) << 3);
      int c1 = 32 + c0;
      int e1 = j * DH + ((((c1 >> 3) ^ (j & 7)) << 3));
      bf16x8 b0 = *(const bf16x8*)&Ks[e0];
      bf16x8 b1 = *(const bf16x8*)&Ks[e1];
      f32x4 z = {};
      z = mfma16(aq[0], b0, z);
      z = mfma16(aq[1], b1, z);
      sc[jt] = z;
    }

    // mask + key bias + row max
    float mnew[4];
#pragma unroll
    for (int r = 0; r < 4; ++r) mnew[r] = -3e38f;
    const int rbase = iw + ((lane >> 4) << 2);
#pragma unroll
    for (int jt = 0; jt < 8; ++jt) {
      int j = j0 + jt * 16 + (lane & 15);
      float kbv = BiasS[jt * 16 + (lane & 15)];
#pragma unroll
      for (int r = 0; r < 4; ++r) {
        int i = rbase + r;
        float s = sc[jt][r] + kbv;
        s = (j >= i && j <= i + 512) ? s : NEGV;
        sc[jt][r] = s;
        mnew[r] = fmaxf(mnew[r], s);
      }
    }
#pragma unroll
    for (int off = 1; off < 16; off <<= 1)
#pragma unroll
      for (int r = 0; r < 4; ++r)
        mnew[r] = fmaxf(mnew[r], __shfl_xor(mnew[r], off));

    float scale[4], lsum[4];
#pragma unroll
    for (int r = 0; r < 4; ++r) {
      float mn = fmaxf(mrow[r], mnew[r]);
      scale[r] = __expf(mrow[r] - mn);
      mrow[r] = mn;
      lsum[r] = 0.f;
    }
#pragma unroll
    for (int jt = 0; jt < 8; ++jt)
#pragma unroll
      for (int r = 0; r < 4; ++r) {
        float p = __expf(sc[jt][r] - mrow[r]);
        sc[jt][r] = p;
        lsum[r] += p;
      }
#pragma unroll
    for (int off = 1; off < 16; off <<= 1)
#pragma unroll
      for (int r = 0; r < 4; ++r)
        lsum[r] += __shfl_xor(lsum[r], off);
#pragma unroll
    for (int r = 0; r < 4; ++r) lrow[r] = lrow[r] * scale[r] + lsum[r];
#pragma unroll
    for (int nt = 0; nt < 4; ++nt)
#pragma unroll
      for (int r = 0; r < 4; ++r) acc[nt][r] *= scale[r];

    // P -> LDS (padded 132 to break bank periodicity)
    short* pw = Ps[wid];
    {
      int row = (lane >> 4) << 2;
      int colb = lane & 15;
#pragma unroll
      for (int jt = 0; jt < 8; ++jt)
#pragma unroll
        for (int r = 0; r < 4; ++r)
          pw[(row + r) * 132 + jt * 16 + colb] = f2bf(sc[jt][r]);
    }
    // PV
#pragma unroll
    for (int ks = 0; ks < 4; ++ks) {
      bf16x8 pa = *(const bf16x8*)&pw[(lane & 15) * 132 + ks * 32 + ((lane >> 4) << 3)];
#pragma unroll
      for (int nt = 0; nt < 4; ++nt) {
        int d = nt * 16 + (lane & 15);
        int jb = ks * 32 + ((lane >> 4) << 3);
        int e = d * 128 + (((jb >> 3) ^ (d & 7)) << 3);
        bf16x8 vb = *(const bf16x8*)&Vs[e];
        acc[nt] = mfma16(pa, vb, acc[nt]);
      }
    }
  }

  // epilogue: normalize, restage, coalesced store to ctx[b][s][h*64+d]
  float inv[4];
#pragma unroll
  for (int r = 0; r < 4; ++r) inv[r] = 1.0f / lrow[r];
  short* cw = Ps[wid];
  {
    int row = (lane >> 4) << 2;
    int colb = lane & 15;
#pragma unroll
    for (int nt = 0; nt < 4; ++nt)
#pragma unroll
      for (int r = 0; r < 4; ++r)
        cw[(row + r) * 72 + nt * 16 + colb] = f2bf(acc[nt][r] * inv[r]);
  }
#pragma unroll
  for (int it = 0; it < 2; ++it) {
    int row = it * 8 + (lane >> 3);
    int c8 = (lane & 7) << 3;
    bf16x8 val = *(const bf16x8*)&cw[row * 72 + c8];
    *(bf16x8*)(ctx + ((bb * SEQ) + s0 + wid * 16 + row) * DM + h * DH + c8) = val;
  }
}

// ---------------- output projection GEMM ----------------
__global__ __launch_bounds__(256) void gemm_out(
    const short* __restrict__ Cb, const short* __restrict__ Wob,
    const float* __restrict__ bo, float* __restrict__ out) {
  __shared__ __align__(16) short As[128 * 32];
  __shared__ __align__(16) short Bs[128 * 32];
  const int tid = threadIdx.x, lane = tid & 63, wid = tid >> 6;
  const int m0 = blockIdx.x * 128, n0 = blockIdx.y * 128;
  const int wr = (wid >> 1) * 64, wc = (wid & 1) * 64;
  const int K = 768;
  const short* Ag = Cb + (m0 + (tid >> 2)) * K + ((tid & 3) << 3);
  const short* Bg = Wob + (n0 + (tid >> 2)) * K + ((tid & 3) << 3);
  short* Al = As + tid * 8;
  short* Bl = Bs + tid * 8;
  f32x4 acc[4][4] = {};
  for (int kt = 0; kt < K; kt += 32) {
    __syncthreads();
    gload16(Ag + kt, Al);
    gload16(Ag + kt + 64 * K, Al + 2048);
    gload16(Bg + kt, Bl);
    gload16(Bg + kt + 64 * K, Bl + 2048);
    __syncthreads();
    bf16x8 a[4], b[4];
#pragma unroll
    for (int mi = 0; mi < 4; ++mi)
      a[mi] = *(const bf16x8*)&As[(wr + mi * 16 + (lane & 15)) * 32 + ((lane >> 4) << 3)];
#pragma unroll
    for (int ni = 0; ni < 4; ++ni)
      b[ni] = *(const bf16x8*)&Bs[(wc + ni * 16 + (lane & 15)) * 32 + ((lane >> 4) << 3)];
#pragma unroll
    for (int mi = 0; mi < 4; ++mi)
#pragma unroll
      for (int ni = 0; ni < 4; ++ni)
        acc[mi][ni] = mfma16(a[mi], b[ni], acc[mi][ni]);
  }
  float bias[4];
#pragma unroll
  for (int ni = 0; ni < 4; ++ni)
    bias[ni] = bo[n0 + wc + ni * 16 + (lane & 15)];
#pragma unroll
  for (int mi = 0; mi < 4; ++mi)
#pragma unroll
    for (int ni = 0; ni < 4; ++ni) {
      int row = m0 + wr + mi * 16 + ((lane >> 4) << 2);
      int col = n0 + wc + ni * 16 + (lane & 15);
#pragma unroll
      for (int r = 0; r < 4; ++r)
        out[(row + r) * DM + col] = acc[mi][ni][r] + bias[ni];
    }
}

// ---------------- launcher ----------------
extern "C" void kernel_launch(void* const* d_in, const int* in_sizes, int n_in,
                              void* d_out, int out_size, void* d_ws, size_t ws_size,
                              hipStream_t stream) {
  (void)in_sizes; (void)n_in; (void)out_size; (void)ws_size;
  const float* hs    = (const float*)d_in[0];
  const float* amask = (const float*)d_in[1];
  const float* Wq = (const float*)d_in[2];
  const float* bq = (const float*)d_in[3];
  const float* Wk = (const float*)d_in[4];
  const float* bk = (const float*)d_in[5];
  const float* Wv = (const float*)d_in[6];
  const float* bv = (const float*)d_in[7];
  const float* Wo = (const float*)d_in[8];
  const float* bo = (const float*)d_in[9];
  float* out = (float*)d_out;
  char* ws = (char*)d_ws;
  // workspace layout (bytes)
  short* Xb   = (short*)(ws);               // 8192*768*2   = 12,582,912
  short* Wqkv = (short*)(ws + 12582912);    // 2304*768*2   =  3,538,944
  short* Wob  = (short*)(ws + 16121856);    // 768*768*2    =  1,179,648
  short* qB   = (short*)(ws + 17301504);    // 12,582,912
  short* kB   = (short*)(ws + 29884416);    // 12,582,912
  short* vTB  = (short*)(ws + 42467328);    // 12,582,912  (ends 55,050,240)
  short* ctx  = Xb;                          // alias: Xb dead after gemm_qkv

  cvt_x<<<dim3(6144), dim3(256), 0, stream>>>(hs, Xb, 8192 * 768 / 4);
  cvt_w<<<dim3(2304), dim3(256), 0, stream>>>(Wq, Wk, Wv, Wo, Wqkv, Wob);
  gemm_qkv<<<dim3(64, 18), dim3(256), 0, stream>>>(Xb, Wqkv, bq, bk, bv, qB, kB, vTB);
  attn<<<dim3(64, 12, 2), dim3(256), 0, stream>>>(qB, kB, vTB, amask, ctx);
  gemm_out<<<dim3(64, 6), dim3(256), 0, stream>>>(ctx, Wob, bo, out);
}

// Round 3
// 150.357 us; speedup vs baseline: 1.0307x; 1.0307x over previous
//
#include <hip/hip_runtime.h>
#include <hip/hip_bf16.h>
#include <stdint.h>

#define NH 12
#define DH 64
#define SEQ 4096
#define DM 768
#define NEGV -1e9f
#define LOG2E 1.4426950408889634f
#define QSCALE 0.1803368801111601f  // 0.125 * log2(e)

using bf16x8 = __attribute__((ext_vector_type(8))) short;
using f32x4  = __attribute__((ext_vector_type(4))) float;

static __device__ __forceinline__ short f2bf(float f) {
  unsigned u = __builtin_bit_cast(unsigned, f);
  u += 0x7fffu + ((u >> 16) & 1u);
  return (short)(u >> 16);
}

static __device__ __forceinline__ unsigned pack2bf(float lo, float hi) {
  unsigned a = __builtin_bit_cast(unsigned, lo);
  a += 0x7fffu + ((a >> 16) & 1u);
  unsigned b = __builtin_bit_cast(unsigned, hi);
  b += 0x7fffu + ((b >> 16) & 1u);
  return (a >> 16) | (b & 0xffff0000u);
}

static __device__ __forceinline__ void gload16(const void* g, void* l) {
  __builtin_amdgcn_global_load_lds(
      (const __attribute__((address_space(1))) unsigned*)g,
      (__attribute__((address_space(3))) unsigned*)l, 16, 0, 0);
}

static __device__ __forceinline__ f32x4 mfma16(bf16x8 a, bf16x8 b, f32x4 c) {
  return __builtin_amdgcn_mfma_f32_16x16x32_bf16(a, b, c, 0, 0, 0);
}

// ---------------- conversion kernels ----------------
__global__ __launch_bounds__(256) void cvt_x(const float* __restrict__ X,
                                             short* __restrict__ Xb, int n4) {
  int i = blockIdx.x * 256 + threadIdx.x;
  if (i >= n4) return;
  float4 v = ((const float4*)X)[i];
  short4 o; o.x = f2bf(v.x); o.y = f2bf(v.y); o.z = f2bf(v.z); o.w = f2bf(v.w);
  ((short4*)Xb)[i] = o;
}

__global__ __launch_bounds__(256) void cvt_w(
    const float* __restrict__ Wq, const float* __restrict__ Wk,
    const float* __restrict__ Wv, const float* __restrict__ Wo,
    short* __restrict__ Wqkv, short* __restrict__ Wob) {
  int i = blockIdx.x * 256 + threadIdx.x;  // unit = 4 elems
  const int n1 = 2304 * 768 / 4;
  if (i < n1) {
    int e = i * 4;
    int row = e / 768;
    const float* src;
    float sc = 1.0f;
    if (row < 768)       { src = Wq + e; sc = QSCALE; }  // fold (1/8)*log2e
    else if (row < 1536) { src = Wk + e - 768 * 768; }
    else                 { src = Wv + e - 1536 * 768; }
    float4 v = *(const float4*)src;
    short4 o; o.x = f2bf(v.x * sc); o.y = f2bf(v.y * sc);
    o.z = f2bf(v.z * sc); o.w = f2bf(v.w * sc);
    ((short4*)Wqkv)[i] = o;
  } else {
    int j = i - n1;
    if (j >= 768 * 768 / 4) return;
    float4 v = ((const float4*)Wo)[j];
    short4 o; o.x = f2bf(v.x); o.y = f2bf(v.y); o.z = f2bf(v.z); o.w = f2bf(v.w);
    ((short4*)Wob)[j] = o;
  }
}

// ---------------- QKV projection GEMM (m97 structure) ----------------
__global__ __launch_bounds__(256) void gemm_qkv(
    const short* __restrict__ Xb, const short* __restrict__ Wqkv,
    const float* __restrict__ bq, const float* __restrict__ bk,
    const float* __restrict__ bv,
    short* __restrict__ qO, short* __restrict__ kO, short* __restrict__ vT) {
  __shared__ __align__(16) short sm[128 * 132];
  short* As = sm;
  short* Bs = sm + 4096;
  const int tid = threadIdx.x, lane = tid & 63, wid = tid >> 6;
  const int m0 = blockIdx.x * 128, n0 = blockIdx.y * 128;
  const int wr = (wid >> 1) * 64, wc = (wid & 1) * 64;
  const int K = 768;
  const short* Ag = Xb + (m0 + (tid >> 2)) * K + ((tid & 3) << 3);
  const short* Bg = Wqkv + (n0 + (tid >> 2)) * K + ((tid & 3) << 3);
  short* Al = As + tid * 8;
  short* Bl = Bs + tid * 8;
  f32x4 acc[4][4] = {};
  for (int kt = 0; kt < K; kt += 32) {
    __syncthreads();
    gload16(Ag + kt, Al);
    gload16(Ag + kt + 64 * K, Al + 2048);
    gload16(Bg + kt, Bl);
    gload16(Bg + kt + 64 * K, Bl + 2048);
    __syncthreads();
    bf16x8 a[4], b[4];
#pragma unroll
    for (int mi = 0; mi < 4; ++mi)
      a[mi] = *(const bf16x8*)&As[(wr + mi * 16 + (lane & 15)) * 32 + ((lane >> 4) << 3)];
#pragma unroll
    for (int ni = 0; ni < 4; ++ni)
      b[ni] = *(const bf16x8*)&Bs[(wc + ni * 16 + (lane & 15)) * 32 + ((lane >> 4) << 3)];
#pragma unroll
    for (int mi = 0; mi < 4; ++mi)
#pragma unroll
      for (int ni = 0; ni < 4; ++ni)
        acc[mi][ni] = mfma16(a[mi], b[ni], acc[mi][ni]);
  }
  const int src = n0 / 768;  // 0=q 1=k 2=v
  const int bb = m0 >> 12;
  const int s0 = m0 & (SEQ - 1);
  const int nloc = n0 % 768;
  float bias[4];
#pragma unroll
  for (int ni = 0; ni < 4; ++ni) {
    int c = wc + ni * 16 + (lane & 15);
    bias[ni] = (src == 0) ? bq[nloc + c] * QSCALE
             : (src == 1) ? bk[nloc + c] : bv[nloc + c];
  }
  __syncthreads();
  if (src < 2) {
#pragma unroll
    for (int mi = 0; mi < 4; ++mi)
#pragma unroll
      for (int ni = 0; ni < 4; ++ni) {
        int row = wr + mi * 16 + ((lane >> 4) << 2);
        int col = wc + ni * 16 + (lane & 15);
#pragma unroll
        for (int r = 0; r < 4; ++r)
          sm[(row + r) * 132 + col] = f2bf(acc[mi][ni][r] + bias[ni]);
      }
    __syncthreads();
    short* dst = (src == 0) ? qO : kO;
    for (int u = tid; u < 8192; u += 256) {
      int r = u >> 6, cp = (u & 63) << 1;
      unsigned val = *(const unsigned*)&sm[r * 132 + cp];
      int c = nloc + cp;
      int h = c >> 6, d = c & 63;
      *(unsigned*)&dst[(((bb * NH + h) * SEQ) + s0 + r) * DH + d] = val;
    }
  } else {
#pragma unroll
    for (int mi = 0; mi < 4; ++mi)
#pragma unroll
      for (int ni = 0; ni < 4; ++ni) {
        int row = wr + mi * 16 + ((lane >> 4) << 2);
        int col = wc + ni * 16 + (lane & 15);
        short4 pk;
        pk.x = f2bf(acc[mi][ni][0] + bias[ni]);
        pk.y = f2bf(acc[mi][ni][1] + bias[ni]);
        pk.z = f2bf(acc[mi][ni][2] + bias[ni]);
        pk.w = f2bf(acc[mi][ni][3] + bias[ni]);
        *(short4*)&sm[col * 132 + row] = pk;
      }
    __syncthreads();
    for (int u = tid; u < 8192; u += 256) {
      int cc = u >> 6, rp = (u & 63) << 1;
      unsigned val = *(const unsigned*)&sm[cc * 132 + rp];
      int c = nloc + cc;
      int h = c >> 6, d = c & 63;
      *(unsigned*)&vT[(((bb * NH + h) * DH) + d) * SEQ + s0 + rp] = val;
    }
  }
}

// ---------------- sliding-window attention ----------------
// 768 blocks (XCD-swizzled), 512 threads = 8 waves, each wave owns 16 q-rows
// of a 128-row strip. Swapped QK^T: lane holds scores for q=lane&15.
__global__ __launch_bounds__(512, 4) void attn(
    const short* __restrict__ qI, const short* __restrict__ kI,
    const short* __restrict__ vT, const float* __restrict__ amask,
    short* __restrict__ ctx) {
  __shared__ __align__(16) short Ks[128 * 64];   // [key][d], XOR-swizzled 16B chunks
  __shared__ __align__(16) short Vs[64 * 128];   // [d][key], XOR-swizzled
  __shared__ __align__(16) short Ps[8][16 * 132];
  const int tid = threadIdx.x, lane = tid & 63, wid = tid >> 6;
  // XCD swizzle: 768 = 8 XCDs x 96 contiguous virtual ids
  const int vb_id = (blockIdx.x & 7) * 96 + (blockIdx.x >> 3);
  const int strip = vb_id & 31;
  const int hh = (vb_id >> 5) % 12;
  const int bb = vb_id / 384;
  const int s0 = strip * 128;
  const int n = s0 >> 8;
  const int i0 = s0 & 255;   // 0 or 128
  const int bh = bb * NH + hh;
  const int m = lane & 15, hq = lane >> 4;
  const int swz = m & 7;
  const int iw = i0 + (wid << 4);

  // Q fragments (B-operand): Q[q=m][dh = 8*hq + e + 32*ks]
  const short* qbase = qI + ((size_t)(bh * SEQ) + s0 + (wid << 4)) * DH;
  const bf16x8 aq0 = *(const bf16x8*)(qbase + m * DH + (hq << 3));
  const bf16x8 aq1 = *(const bf16x8*)(qbase + m * DH + 32 + (hq << 3));

  // hoisted LDS read offsets (short-index), chunk-invariant
  const int kb_s0 = m * 64 + ((hq ^ swz) << 3);
  const int kb_s1 = m * 64 + (((hq + 4) ^ swz) << 3);
  const int vk0 = m * 128 + ((hq ^ swz) << 3);
  const int vk1 = m * 128 + (((hq + 4) ^ swz) << 3);
  const int vk2 = m * 128 + (((hq + 8) ^ swz) << 3);
  const int vk3 = m * 128 + (((hq + 12) ^ swz) << 3);
  short* Pw = Ps[wid];
  const int pwr = m * 132;

  // hoisted staging offsets (2 passes of 512 thr x 16B each for K and V)
  const int e0 = tid * 8, e1 = tid * 8 + 4096;
  const int kj0 = e0 >> 6, kj1 = e1 >> 6;
  const int ksrc0 = kj0 * DH + ((((e0 >> 3) & 7) ^ (kj0 & 7)) << 3);
  const int ksrc1 = kj1 * DH + ((((e1 >> 3) & 7) ^ (kj1 & 7)) << 3);
  const int vd0 = e0 >> 7, vd1 = e1 >> 7;
  const int vsrc0 = vd0 * SEQ + ((((e0 >> 3) & 15) ^ (vd0 & 7)) << 3);
  const int vsrc1 = vd1 * SEQ + ((((e1 >> 3) & 15) ^ (vd1 & 7)) << 3);

  const short* kg0 = kI + (size_t)bh * SEQ * DH;
  const short* vg0 = vT + (size_t)bh * DH * SEQ;
  const float* mk0 = amask + bb * SEQ + (hq << 2);

  f32x4 acc[4] = {};
  float mrow = -1e30f, lrow = 0.f;

#pragma unroll 1
  for (int c = 0; c < 6; ++c) {
    const int j0 = c << 7;
    const int kpos0 = ((n - 1) << 8) + j0;
    if (kpos0 < 0 || kpos0 >= SEQ) continue;           // OOB chunk (uniform)
    if (j0 + 127 < i0 || j0 > i0 + 639) continue;      // band-miss (uniform)

    __syncthreads();
    {
      const short* kb = kg0 + (size_t)kpos0 * DH;
      gload16(kb + ksrc0, (short*)Ks + e0);
      gload16(kb + ksrc1, (short*)Ks + e1);
      const short* vbp = vg0 + kpos0;
      gload16(vbp + vsrc0, (short*)Vs + e0);
      gload16(vbp + vsrc1, (short*)Vs + e1);
    }
    __syncthreads();

    // QK^T (swapped): sc[jt][r] = S[key=16jt+4hq+r][q=m]
    f32x4 sc[8];
    __builtin_amdgcn_s_setprio(1);
#pragma unroll
    for (int jt = 0; jt < 8; ++jt) {
      bf16x8 k0 = *(const bf16x8*)(Ks + jt * 1024 + kb_s0);
      bf16x8 k1 = *(const bf16x8*)(Ks + jt * 1024 + kb_s1);
      f32x4 z = {};
      z = mfma16(k0, aq0, z);
      z = mfma16(k1, aq1, z);
      sc[jt] = z;
    }
    __builtin_amdgcn_s_setprio(0);

    // bias + (edge-only) band mask + row max; all in log2 domain
    const float* mp = mk0 + kpos0;
    float mn = mrow;
    const bool interior = (j0 >= iw + 15) && (j0 <= iw + 385);
    if (interior) {
#pragma unroll
      for (int jt = 0; jt < 8; ++jt) {
        float4 b4 = *(const float4*)(mp + jt * 16);
#pragma unroll
        for (int r = 0; r < 4; ++r) {
          float s = fmaf(-LOG2E, (&b4.x)[r], sc[jt][r]);
          sc[jt][r] = s;
          mn = fmaxf(mn, s);
        }
      }
    } else {
      const int iq = iw + m;
#pragma unroll
      for (int jt = 0; jt < 8; ++jt) {
        float4 b4 = *(const float4*)(mp + jt * 16);
        const int jb = j0 + jt * 16 + (hq << 2);
#pragma unroll
        for (int r = 0; r < 4; ++r) {
          int j = jb + r;
          float s = fmaf(-LOG2E, (&b4.x)[r], sc[jt][r]);
          s = (j >= iq && j <= iq + 512) ? s : NEGV;
          sc[jt][r] = s;
          mn = fmaxf(mn, s);
        }
      }
    }
    mn = fmaxf(mn, __shfl_xor(mn, 16));
    mn = fmaxf(mn, __shfl_xor(mn, 32));

    // exp2 + pack P into LDS (paired bf16 packing)
    float l0 = 0.f;
#pragma unroll
    for (int jt = 0; jt < 8; ++jt) {
      float p0 = exp2f(sc[jt][0] - mn);
      float p1 = exp2f(sc[jt][1] - mn);
      float p2 = exp2f(sc[jt][2] - mn);
      float p3 = exp2f(sc[jt][3] - mn);
      l0 += (p0 + p1) + (p2 + p3);
      uint2 u;
      u.x = pack2bf(p0, p1);
      u.y = pack2bf(p2, p3);
      *(uint2*)(Pw + pwr + jt * 16 + (hq << 2)) = u;
    }
    l0 += __shfl_xor(l0, 16);
    l0 += __shfl_xor(l0, 32);
    const float scl = exp2f(mrow - mn);
    lrow = lrow * scl + l0;
    mrow = mn;
    // rescale acc rows (acc row q' = 4*hq + r; its scale lives in lane q')
    const float s0r = __shfl(scl, (hq << 2) + 0);
    const float s1r = __shfl(scl, (hq << 2) + 1);
    const float s2r = __shfl(scl, (hq << 2) + 2);
    const float s3r = __shfl(scl, (hq << 2) + 3);
#pragma unroll
    for (int nt = 0; nt < 4; ++nt) {
      acc[nt][0] *= s0r; acc[nt][1] *= s1r;
      acc[nt][2] *= s2r; acc[nt][3] *= s3r;
    }

    // fence: P writes (this wave's lanes) must land before pa reads (rule 18)
    asm volatile("s_waitcnt lgkmcnt(0)" ::: "memory");
    __builtin_amdgcn_sched_barrier(0);

    // PV
    __builtin_amdgcn_s_setprio(1);
#pragma unroll
    for (int ks = 0; ks < 4; ++ks) {
      bf16x8 pa = *(const bf16x8*)(Pw + pwr + ks * 32 + (hq << 3));
      const int vkk = (ks == 0) ? vk0 : (ks == 1) ? vk1 : (ks == 2) ? vk2 : vk3;
#pragma unroll
      for (int nt = 0; nt < 4; ++nt) {
        bf16x8 vv = *(const bf16x8*)(Vs + nt * 2048 + vkk);
        acc[nt] = mfma16(pa, vv, acc[nt]);
      }
    }
    __builtin_amdgcn_s_setprio(0);
  }

  // epilogue: normalize, restage via Pw, coalesced bf16x8 stores
  const float inv = 1.0f / lrow;
  const float i0r = __shfl(inv, (hq << 2) + 0);
  const float i1r = __shfl(inv, (hq << 2) + 1);
  const float i2r = __shfl(inv, (hq << 2) + 2);
  const float i3r = __shfl(inv, (hq << 2) + 3);
#pragma unroll
  for (int nt = 0; nt < 4; ++nt) {
    Pw[((hq << 2) + 0) * 72 + nt * 16 + m] = f2bf(acc[nt][0] * i0r);
    Pw[((hq << 2) + 1) * 72 + nt * 16 + m] = f2bf(acc[nt][1] * i1r);
    Pw[((hq << 2) + 2) * 72 + nt * 16 + m] = f2bf(acc[nt][2] * i2r);
    Pw[((hq << 2) + 3) * 72 + nt * 16 + m] = f2bf(acc[nt][3] * i3r);
  }
  asm volatile("s_waitcnt lgkmcnt(0)" ::: "memory");
  __builtin_amdgcn_sched_barrier(0);
#pragma unroll
  for (int it = 0; it < 2; ++it) {
    int row = it * 8 + (lane >> 3);
    bf16x8 val = *(const bf16x8*)(Pw + row * 72 + ((lane & 7) << 3));
    *(bf16x8*)(ctx + ((size_t)(bb * SEQ) + s0 + (wid << 4) + row) * DM +
               hh * DH + ((lane & 7) << 3)) = val;
  }
}

// ---------------- output projection GEMM ----------------
__global__ __launch_bounds__(256) void gemm_out(
    const short* __restrict__ Cb, const short* __restrict__ Wob,
    const float* __restrict__ bo, float* __restrict__ out) {
  __shared__ __align__(16) short As[128 * 32];
  __shared__ __align__(16) short Bs[128 * 32];
  const int tid = threadIdx.x, lane = tid & 63, wid = tid >> 6;
  const int m0 = blockIdx.x * 128, n0 = blockIdx.y * 128;
  const int wr = (wid >> 1) * 64, wc = (wid & 1) * 64;
  const int K = 768;
  const short* Ag = Cb + (m0 + (tid >> 2)) * K + ((tid & 3) << 3);
  const short* Bg = Wob + (n0 + (tid >> 2)) * K + ((tid & 3) << 3);
  short* Al = As + tid * 8;
  short* Bl = Bs + tid * 8;
  f32x4 acc[4][4] = {};
  for (int kt = 0; kt < K; kt += 32) {
    __syncthreads();
    gload16(Ag + kt, Al);
    gload16(Ag + kt + 64 * K, Al + 2048);
    gload16(Bg + kt, Bl);
    gload16(Bg + kt + 64 * K, Bl + 2048);
    __syncthreads();
    bf16x8 a[4], b[4];
#pragma unroll
    for (int mi = 0; mi < 4; ++mi)
      a[mi] = *(const bf16x8*)&As[(wr + mi * 16 + (lane & 15)) * 32 + ((lane >> 4) << 3)];
#pragma unroll
    for (int ni = 0; ni < 4; ++ni)
      b[ni] = *(const bf16x8*)&Bs[(wc + ni * 16 + (lane & 15)) * 32 + ((lane >> 4) << 3)];
#pragma unroll
    for (int mi = 0; mi < 4; ++mi)
#pragma unroll
      for (int ni = 0; ni < 4; ++ni)
        acc[mi][ni] = mfma16(a[mi], b[ni], acc[mi][ni]);
  }
  float bias[4];
#pragma unroll
  for (int ni = 0; ni < 4; ++ni)
    bias[ni] = bo[n0 + wc + ni * 16 + (lane & 15)];
#pragma unroll
  for (int mi = 0; mi < 4; ++mi)
#pragma unroll
    for (int ni = 0; ni < 4; ++ni) {
      int row = m0 + wr + mi * 16 + ((lane >> 4) << 2);
      int col = n0 + wc + ni * 16 + (lane & 15);
#pragma unroll
      for (int r = 0; r < 4; ++r)
        out[(row + r) * DM + col] = acc[mi][ni][r] + bias[ni];
    }
}

// ---------------- launcher ----------------
extern "C" void kernel_launch(void* const* d_in, const int* in_sizes, int n_in,
                              void* d_out, int out_size, void* d_ws, size_t ws_size,
                              hipStream_t stream) {
  (void)in_sizes; (void)n_in; (void)out_size; (void)ws_size;
  const float* hs    = (const float*)d_in[0];
  const float* amask = (const float*)d_in[1];
  const float* Wq = (const float*)d_in[2];
  const float* bq = (const float*)d_in[3];
  const float* Wk = (const float*)d_in[4];
  const float* bk = (const float*)d_in[5];
  const float* Wv = (const float*)d_in[6];
  const float* bv = (const float*)d_in[7];
  const float* Wo = (const float*)d_in[8];
  const float* bo = (const float*)d_in[9];
  float* out = (float*)d_out;
  char* ws = (char*)d_ws;
  short* Xb   = (short*)(ws);
  short* Wqkv = (short*)(ws + 12582912);
  short* Wob  = (short*)(ws + 16121856);
  short* qB   = (short*)(ws + 17301504);
  short* kB   = (short*)(ws + 29884416);
  short* vTB  = (short*)(ws + 42467328);
  short* ctx  = Xb;  // Xb dead after gemm_qkv

  cvt_x<<<dim3(6144), dim3(256), 0, stream>>>(hs, Xb, 8192 * 768 / 4);
  cvt_w<<<dim3(2304), dim3(256), 0, stream>>>(Wq, Wk, Wv, Wo, Wqkv, Wob);
  gemm_qkv<<<dim3(64, 18), dim3(256), 0, stream>>>(Xb, Wqkv, bq, bk, bv, qB, kB, vTB);
  attn<<<dim3(768), dim3(512), 0, stream>>>(qB, kB, vTB, amask, ctx);
  gemm_out<<<dim3(64, 6), dim3(256), 0, stream>>>(ctx, Wob, bo, out);
}

// Round 6
// 134.765 us; speedup vs baseline: 1.1499x; 1.1157x over previous
//
#include <hip/hip_runtime.h>
#include <hip/hip_bf16.h>
#include <stdint.h>

#define NH 12
#define DH 64
#define SEQ 4096
#define DM 768
#define NEGV -1e9f
#define LOG2E 1.4426950408889634f
#define QSCALE 0.1803368801111601f  // 0.125 * log2(e)

using bf16x8 = __attribute__((ext_vector_type(8))) short;
using f32x4  = __attribute__((ext_vector_type(4))) float;

static __device__ __forceinline__ short f2bf(float f) {
  unsigned u = __builtin_bit_cast(unsigned, f);
  u += 0x7fffu + ((u >> 16) & 1u);
  return (short)(u >> 16);
}

static __device__ __forceinline__ unsigned pack2bf(float lo, float hi) {
  unsigned a = __builtin_bit_cast(unsigned, lo);
  a += 0x7fffu + ((a >> 16) & 1u);
  unsigned b = __builtin_bit_cast(unsigned, hi);
  b += 0x7fffu + ((b >> 16) & 1u);
  return (a >> 16) | (b & 0xffff0000u);
}

static __device__ __forceinline__ void gload16(const void* g, void* l) {
  __builtin_amdgcn_global_load_lds(
      (const __attribute__((address_space(1))) unsigned*)g,
      (__attribute__((address_space(3))) unsigned*)l, 16, 0, 0);
}

static __device__ __forceinline__ f32x4 mfma16(bf16x8 a, bf16x8 b, f32x4 c) {
  return __builtin_amdgcn_mfma_f32_16x16x32_bf16(a, b, c, 0, 0, 0);
}

#define SBAR() __builtin_amdgcn_sched_barrier(0)
#define WAIT8() asm volatile("s_waitcnt vmcnt(8)" ::: "memory")
#define WAIT4() asm volatile("s_waitcnt vmcnt(4)" ::: "memory")
#define WAIT0() asm volatile("s_waitcnt vmcnt(0)" ::: "memory")
#define HBAR() __builtin_amdgcn_s_barrier()

// ---------------- conversion kernels ----------------
__global__ __launch_bounds__(256) void cvt_x(const float* __restrict__ X,
                                             short* __restrict__ Xb, int n4) {
  int i = blockIdx.x * 256 + threadIdx.x;
  if (i >= n4) return;
  float4 v = ((const float4*)X)[i];
  short4 o; o.x = f2bf(v.x); o.y = f2bf(v.y); o.z = f2bf(v.z); o.w = f2bf(v.w);
  ((short4*)Xb)[i] = o;
}

__global__ __launch_bounds__(256) void cvt_w(
    const float* __restrict__ Wq, const float* __restrict__ Wk,
    const float* __restrict__ Wv, const float* __restrict__ Wo,
    short* __restrict__ Wqkv, short* __restrict__ Wob) {
  int i = blockIdx.x * 256 + threadIdx.x;  // unit = 4 elems
  const int n1 = 2304 * 768 / 4;
  if (i < n1) {
    int e = i * 4;
    int row = e / 768;
    const float* src;
    float sc = 1.0f;
    if (row < 768)       { src = Wq + e; sc = QSCALE; }
    else if (row < 1536) { src = Wk + e - 768 * 768; }
    else                 { src = Wv + e - 1536 * 768; }
    float4 v = *(const float4*)src;
    short4 o; o.x = f2bf(v.x * sc); o.y = f2bf(v.y * sc);
    o.z = f2bf(v.z * sc); o.w = f2bf(v.w * sc);
    ((short4*)Wqkv)[i] = o;
  } else {
    int j = i - n1;
    if (j >= 768 * 768 / 4) return;
    float4 v = ((const float4*)Wo)[j];
    short4 o; o.x = f2bf(v.x); o.y = f2bf(v.y); o.z = f2bf(v.z); o.w = f2bf(v.w);
    ((short4*)Wob)[j] = o;
  }
}

// ======= pipelined 128x128xBK32 GEMM core (4-buffer, depth-3, counted vmcnt) =======
// LDS: A bufs [4][128][32] at sm[0..16383], B bufs at sm[16384..32767] (shorts)
// XOR swizzle (both sides): granule' = g ^ ((row>>1)&3)
#define GEMM_PIPELINE(SM, AG, BG, ACC, LANE, WR, WC)                           \
  {                                                                            \
    const int l15 = (LANE) & 15, gw = (LANE) >> 4;                             \
    const int s_ = (l15 >> 1) & 3;                                             \
    const int fcol = ((gw ^ s_) << 3);                                         \
    const int NT = 24; /* 768/32 */                                            \
    auto stage = [&](int t) {                                                  \
      short* ab = (SM) + ((t & 3) << 12);                                      \
      short* bb = (SM) + 16384 + ((t & 3) << 12);                              \
      int kt = t << 5;                                                         \
      gload16((AG) + kt, ab + ldst);                                           \
      gload16((AG) + kt + 64 * 768, ab + ldst + 2048);                         \
      gload16((BG) + kt, bb + ldst);                                           \
      gload16((BG) + kt + 64 * 768, bb + ldst + 2048);                         \
    };                                                                         \
    auto compute = [&](int t) {                                                \
      const short* ab = (SM) + ((t & 3) << 12);                                \
      const short* bb = (SM) + 16384 + ((t & 3) << 12);                        \
      bf16x8 af[4], bf[4];                                                     \
      _Pragma("unroll") for (int mi = 0; mi < 4; ++mi)                         \
          af[mi] = *(const bf16x8*)(ab + ((WR) + mi * 16 + l15) * 32 + fcol);  \
      _Pragma("unroll") for (int ni = 0; ni < 4; ++ni)                         \
          bf[ni] = *(const bf16x8*)(bb + ((WC) + ni * 16 + l15) * 32 + fcol);  \
      __builtin_amdgcn_s_setprio(1);                                           \
      _Pragma("unroll") for (int mi = 0; mi < 4; ++mi)                         \
          _Pragma("unroll") for (int ni = 0; ni < 4; ++ni)                     \
              ACC[mi][ni] = mfma16(af[mi], bf[ni], ACC[mi][ni]);               \
      __builtin_amdgcn_s_setprio(0);                                           \
    };                                                                         \
    stage(0); stage(1); stage(2);                                              \
    SBAR();                                                                    \
    _Pragma("unroll 1") for (int i = 0; i < NT - 3; ++i) {                     \
      SBAR(); WAIT8(); HBAR(); SBAR();                                         \
      stage(i + 3);                                                            \
      SBAR();                                                                  \
      compute(i);                                                              \
    }                                                                          \
    SBAR(); WAIT8(); HBAR(); SBAR(); compute(NT - 3);                          \
    SBAR(); WAIT4(); HBAR(); SBAR(); compute(NT - 2);                          \
    SBAR(); WAIT0(); HBAR(); SBAR(); compute(NT - 1);                          \
  }

// ---------------- QKV projection GEMM ----------------
// 1D grid 1152, XCD-chunked: each XCD owns an 8-m-block A panel x all 18 n.
__global__ __launch_bounds__(256) void gemm_qkv(
    const short* __restrict__ Xb, const short* __restrict__ Wqkv,
    const float* __restrict__ bq, const float* __restrict__ bk,
    const float* __restrict__ bv,
    short* __restrict__ qO, short* __restrict__ kO, short* __restrict__ vT) {
  __shared__ __align__(16) short sm[32768];
  const int tid = threadIdx.x, lane = tid & 63, wid = tid >> 6;
  const int xcd = blockIdx.x & 7, kk = blockIdx.x >> 3;  // kk in [0,144)
  const int m0 = (xcd * 8 + (kk & 7)) * 128;
  const int n0 = (kk >> 3) * 128;
  const int wr = (wid >> 1) * 64, wc = (wid & 1) * 64;
  const int srow = tid >> 2;
  const int scol = (((tid & 3) ^ ((srow >> 1) & 3)) << 3);
  const short* Ag = Xb + (m0 + srow) * 768 + scol;
  const short* Bg = Wqkv + (n0 + srow) * 768 + scol;
  const int ldst = tid * 8;

  // bias loads BEFORE pipeline, then drain so vmcnt counting stays exact
  const int src = n0 / 768;  // 0=q 1=k 2=v
  const int nloc = n0 % 768;
  float bias[4];
#pragma unroll
  for (int ni = 0; ni < 4; ++ni) {
    int c = nloc + wc + ni * 16 + (lane & 15);
    bias[ni] = (src == 0) ? bq[c] * QSCALE : (src == 1) ? bk[c] : bv[c];
  }
  WAIT0(); SBAR();

  f32x4 acc[4][4] = {};
  GEMM_PIPELINE(sm, Ag, Bg, acc, lane, wr, wc);

  const int bb = m0 >> 12;
  const int s0 = m0 & (SEQ - 1);
  __syncthreads();
  if (src < 2) {
#pragma unroll
    for (int mi = 0; mi < 4; ++mi)
#pragma unroll
      for (int ni = 0; ni < 4; ++ni) {
        int row = wr + mi * 16 + ((lane >> 4) << 2);
        int col = wc + ni * 16 + (lane & 15);
#pragma unroll
        for (int r = 0; r < 4; ++r)
          sm[(row + r) * 132 + col] = f2bf(acc[mi][ni][r] + bias[ni]);
      }
    __syncthreads();
    short* dst = (src == 0) ? qO : kO;
    for (int u = tid; u < 8192; u += 256) {
      int r = u >> 6, cp = (u & 63) << 1;
      unsigned val = *(const unsigned*)&sm[r * 132 + cp];
      int c = nloc + cp;
      int h = c >> 6, d = c & 63;
      *(unsigned*)&dst[(((bb * NH + h) * SEQ) + s0 + r) * DH + d] = val;
    }
  } else {
#pragma unroll
    for (int mi = 0; mi < 4; ++mi)
#pragma unroll
      for (int ni = 0; ni < 4; ++ni) {
        int row = wr + mi * 16 + ((lane >> 4) << 2);
        int col = wc + ni * 16 + (lane & 15);
        short4 pk;
        pk.x = f2bf(acc[mi][ni][0] + bias[ni]);
        pk.y = f2bf(acc[mi][ni][1] + bias[ni]);
        pk.z = f2bf(acc[mi][ni][2] + bias[ni]);
        pk.w = f2bf(acc[mi][ni][3] + bias[ni]);
        *(short4*)&sm[col * 132 + row] = pk;
      }
    __syncthreads();
    for (int u = tid; u < 8192; u += 256) {
      int cc = u >> 6, rp = (u & 63) << 1;
      unsigned val = *(const unsigned*)&sm[cc * 132 + rp];
      int c = nloc + cc;
      int h = c >> 6, d = c & 63;
      *(unsigned*)&vT[(((bb * NH + h) * DH) + d) * SEQ + s0 + rp] = val;
    }
  }
}

// ---------------- sliding-window attention ----------------
__global__ __launch_bounds__(512, 4) void attn(
    const short* __restrict__ qI, const short* __restrict__ kI,
    const short* __restrict__ vT, const float* __restrict__ amask,
    short* __restrict__ ctx) {
  __shared__ __align__(16) short Ks[128 * 64];
  __shared__ __align__(16) short Vs[64 * 128];
  __shared__ __align__(16) short Ps[8][16 * 132];
  const int tid = threadIdx.x, lane = tid & 63, wid = tid >> 6;
  const int vb_id = (blockIdx.x & 7) * 96 + (blockIdx.x >> 3);
  const int strip = vb_id & 31;
  const int hh = (vb_id >> 5) % 12;
  const int bb = vb_id / 384;
  const int s0 = strip * 128;
  const int n = s0 >> 8;
  const int i0 = s0 & 255;
  const int bh = bb * NH + hh;
  const int m = lane & 15, hq = lane >> 4;
  const int swz = m & 7;
  const int iw = i0 + (wid << 4);

  const short* qbase = qI + ((size_t)(bh * SEQ) + s0 + (wid << 4)) * DH;
  const bf16x8 aq0 = *(const bf16x8*)(qbase + m * DH + (hq << 3));
  const bf16x8 aq1 = *(const bf16x8*)(qbase + m * DH + 32 + (hq << 3));

  const int kb_s0 = m * 64 + ((hq ^ swz) << 3);
  const int kb_s1 = m * 64 + (((hq + 4) ^ swz) << 3);
  const int vk0 = m * 128 + ((hq ^ swz) << 3);
  const int vk1 = m * 128 + (((hq + 4) ^ swz) << 3);
  const int vk2 = m * 128 + (((hq + 8) ^ swz) << 3);
  const int vk3 = m * 128 + (((hq + 12) ^ swz) << 3);
  short* Pw = Ps[wid];
  const int pwr = m * 132;

  const int e0 = tid * 8, e1 = tid * 8 + 4096;
  const int kj0 = e0 >> 6, kj1 = e1 >> 6;
  const int ksrc0 = kj0 * DH + ((((e0 >> 3) & 7) ^ (kj0 & 7)) << 3);
  const int ksrc1 = kj1 * DH + ((((e1 >> 3) & 7) ^ (kj1 & 7)) << 3);
  const int vd0 = e0 >> 7, vd1 = e1 >> 7;
  const int vsrc0 = vd0 * SEQ + ((((e0 >> 3) & 15) ^ (vd0 & 7)) << 3);
  const int vsrc1 = vd1 * SEQ + ((((e1 >> 3) & 15) ^ (vd1 & 7)) << 3);

  const short* kg0 = kI + (size_t)bh * SEQ * DH;
  const short* vg0 = vT + (size_t)bh * DH * SEQ;
  const float* mk0 = amask + bb * SEQ + (hq << 2);

  f32x4 acc[4] = {};
  float mrow = -1e30f, lrow = 0.f;

#pragma unroll 1
  for (int c = 0; c < 6; ++c) {
    const int j0 = c << 7;
    const int kpos0 = ((n - 1) << 8) + j0;
    if (kpos0 < 0 || kpos0 >= SEQ) continue;
    if (j0 + 127 < i0 || j0 > i0 + 639) continue;

    __syncthreads();
    {
      const short* kb = kg0 + (size_t)kpos0 * DH;
      gload16(kb + ksrc0, (short*)Ks + e0);
      gload16(kb + ksrc1, (short*)Ks + e1);
      const short* vbp = vg0 + kpos0;
      gload16(vbp + vsrc0, (short*)Vs + e0);
      gload16(vbp + vsrc1, (short*)Vs + e1);
    }
    __syncthreads();

    f32x4 sc[8];
    __builtin_amdgcn_s_setprio(1);
#pragma unroll
    for (int jt = 0; jt < 8; ++jt) {
      bf16x8 k0 = *(const bf16x8*)(Ks + jt * 1024 + kb_s0);
      bf16x8 k1 = *(const bf16x8*)(Ks + jt * 1024 + kb_s1);
      f32x4 z = {};
      z = mfma16(k0, aq0, z);
      z = mfma16(k1, aq1, z);
      sc[jt] = z;
    }
    __builtin_amdgcn_s_setprio(0);

    const float* mp = mk0 + kpos0;
    float mn = mrow;
    const bool interior = (j0 >= iw + 15) && (j0 <= iw + 385);
    if (interior) {
#pragma unroll
      for (int jt = 0; jt < 8; ++jt) {
        float4 b4 = *(const float4*)(mp + jt * 16);
#pragma unroll
        for (int r = 0; r < 4; ++r) {
          float s = fmaf(-LOG2E, (&b4.x)[r], sc[jt][r]);
          sc[jt][r] = s;
          mn = fmaxf(mn, s);
        }
      }
    } else {
      const int iq = iw + m;
#pragma unroll
      for (int jt = 0; jt < 8; ++jt) {
        float4 b4 = *(const float4*)(mp + jt * 16);
        const int jb = j0 + jt * 16 + (hq << 2);
#pragma unroll
        for (int r = 0; r < 4; ++r) {
          int j = jb + r;
          float s = fmaf(-LOG2E, (&b4.x)[r], sc[jt][r]);
          s = (j >= iq && j <= iq + 512) ? s : NEGV;
          sc[jt][r] = s;
          mn = fmaxf(mn, s);
        }
      }
    }
    mn = fmaxf(mn, __shfl_xor(mn, 16));
    mn = fmaxf(mn, __shfl_xor(mn, 32));

    float l0 = 0.f;
#pragma unroll
    for (int jt = 0; jt < 8; ++jt) {
      float p0 = exp2f(sc[jt][0] - mn);
      float p1 = exp2f(sc[jt][1] - mn);
      float p2 = exp2f(sc[jt][2] - mn);
      float p3 = exp2f(sc[jt][3] - mn);
      l0 += (p0 + p1) + (p2 + p3);
      uint2 u;
      u.x = pack2bf(p0, p1);
      u.y = pack2bf(p2, p3);
      *(uint2*)(Pw + pwr + jt * 16 + (hq << 2)) = u;
    }
    l0 += __shfl_xor(l0, 16);
    l0 += __shfl_xor(l0, 32);
    const float scl = exp2f(mrow - mn);
    lrow = lrow * scl + l0;
    mrow = mn;
    const float s0r = __shfl(scl, (hq << 2) + 0);
    const float s1r = __shfl(scl, (hq << 2) + 1);
    const float s2r = __shfl(scl, (hq << 2) + 2);
    const float s3r = __shfl(scl, (hq << 2) + 3);
#pragma unroll
    for (int nt = 0; nt < 4; ++nt) {
      acc[nt][0] *= s0r; acc[nt][1] *= s1r;
      acc[nt][2] *= s2r; acc[nt][3] *= s3r;
    }

    asm volatile("s_waitcnt lgkmcnt(0)" ::: "memory");
    __builtin_amdgcn_sched_barrier(0);

    __builtin_amdgcn_s_setprio(1);
#pragma unroll
    for (int ks = 0; ks < 4; ++ks) {
      bf16x8 pa = *(const bf16x8*)(Pw + pwr + ks * 32 + (hq << 3));
      const int vkk = (ks == 0) ? vk0 : (ks == 1) ? vk1 : (ks == 2) ? vk2 : vk3;
#pragma unroll
      for (int nt = 0; nt < 4; ++nt) {
        bf16x8 vv = *(const bf16x8*)(Vs + nt * 2048 + vkk);
        acc[nt] = mfma16(pa, vv, acc[nt]);
      }
    }
    __builtin_amdgcn_s_setprio(0);
  }

  const float inv = 1.0f / lrow;
  const float i0r = __shfl(inv, (hq << 2) + 0);
  const float i1r = __shfl(inv, (hq << 2) + 1);
  const float i2r = __shfl(inv, (hq << 2) + 2);
  const float i3r = __shfl(inv, (hq << 2) + 3);
#pragma unroll
  for (int nt = 0; nt < 4; ++nt) {
    Pw[((hq << 2) + 0) * 72 + nt * 16 + m] = f2bf(acc[nt][0] * i0r);
    Pw[((hq << 2) + 1) * 72 + nt * 16 + m] = f2bf(acc[nt][1] * i1r);
    Pw[((hq << 2) + 2) * 72 + nt * 16 + m] = f2bf(acc[nt][2] * i2r);
    Pw[((hq << 2) + 3) * 72 + nt * 16 + m] = f2bf(acc[nt][3] * i3r);
  }
  asm volatile("s_waitcnt lgkmcnt(0)" ::: "memory");
  __builtin_amdgcn_sched_barrier(0);
#pragma unroll
  for (int it = 0; it < 2; ++it) {
    int row = it * 8 + (lane >> 3);
    bf16x8 val = *(const bf16x8*)(Pw + row * 72 + ((lane & 7) << 3));
    *(bf16x8*)(ctx + ((size_t)(bb * SEQ) + s0 + (wid << 4) + row) * DM +
               hh * DH + ((lane & 7) << 3)) = val;
  }
}

// ---------------- output projection GEMM (pipelined) ----------------
__global__ __launch_bounds__(256) void gemm_out(
    const short* __restrict__ Cb, const short* __restrict__ Wob,
    const float* __restrict__ bo, float* __restrict__ out) {
  __shared__ __align__(16) short sm[32768];
  const int tid = threadIdx.x, lane = tid & 63, wid = tid >> 6;
  const int xcd = blockIdx.x & 7, kk = blockIdx.x >> 3;  // kk in [0,48)
  const int m0 = (xcd * 8 + (kk & 7)) * 128;
  const int n0 = (kk >> 3) * 128;
  const int wr = (wid >> 1) * 64, wc = (wid & 1) * 64;
  const int srow = tid >> 2;
  const int scol = (((tid & 3) ^ ((srow >> 1) & 3)) << 3);
  const short* Ag = Cb + (m0 + srow) * 768 + scol;
  const short* Bg = Wob + (n0 + srow) * 768 + scol;
  const int ldst = tid * 8;

  float bias[4];
#pragma unroll
  for (int ni = 0; ni < 4; ++ni)
    bias[ni] = bo[n0 + wc + ni * 16 + (lane & 15)];
  WAIT0(); SBAR();

  f32x4 acc[4][4] = {};
  GEMM_PIPELINE(sm, Ag, Bg, acc, lane, wr, wc);

#pragma unroll
  for (int mi = 0; mi < 4; ++mi)
#pragma unroll
    for (int ni = 0; ni < 4; ++ni) {
      int row = m0 + wr + mi * 16 + ((lane >> 4) << 2);
      int col = n0 + wc + ni * 16 + (lane & 15);
#pragma unroll
      for (int r = 0; r < 4; ++r)
        out[(row + r) * DM + col] = acc[mi][ni][r] + bias[ni];
    }
}

// ---------------- launcher ----------------
extern "C" void kernel_launch(void* const* d_in, const int* in_sizes, int n_in,
                              void* d_out, int out_size, void* d_ws, size_t ws_size,
                              hipStream_t stream) {
  (void)in_sizes; (void)n_in; (void)out_size; (void)ws_size;
  const float* hs    = (const float*)d_in[0];
  const float* amask = (const float*)d_in[1];
  const float* Wq = (const float*)d_in[2];
  const float* bq = (const float*)d_in[3];
  const float* Wk = (const float*)d_in[4];
  const float* bk = (const float*)d_in[5];
  const float* Wv = (const float*)d_in[6];
  const float* bv = (const float*)d_in[7];
  const float* Wo = (const float*)d_in[8];
  const float* bo = (const float*)d_in[9];
  float* out = (float*)d_out;
  char* ws = (char*)d_ws;
  short* Xb   = (short*)(ws);
  short* Wqkv = (short*)(ws + 12582912);
  short* Wob  = (short*)(ws + 16121856);
  short* qB   = (short*)(ws + 17301504);
  short* kB   = (short*)(ws + 29884416);
  short* vTB  = (short*)(ws + 42467328);
  short* ctx  = Xb;  // Xb dead after gemm_qkv

  cvt_x<<<dim3(6144), dim3(256), 0, stream>>>(hs, Xb, 8192 * 768 / 4);
  cvt_w<<<dim3(2304), dim3(256), 0, stream>>>(Wq, Wk, Wv, Wo, Wqkv, Wob);
  gemm_qkv<<<dim3(1152), dim3(256), 0, stream>>>(Xb, Wqkv, bq, bk, bv, qB, kB, vTB);
  attn<<<dim3(768), dim3(512), 0, stream>>>(qB, kB, vTB, amask, ctx);
  gemm_out<<<dim3(384), dim3(256), 0, stream>>>(ctx, Wob, bo, out);
}